// Round 6
// baseline (429.432 us; speedup 1.0000x reference)
//
#include <hip/hip_runtime.h>
#include <hip/hip_bf16.h>
#include <hip/hip_cooperative_groups.h>

namespace cg = cooperative_groups;

// Sizes (fixed by the problem)
#define BSZ 2048
#define TSZ 512
#define OSZ 128
#define ESZ 512
#define HSZ 128
#define VSZ 34

// d_out layout (f32): out[2048*34], c[2048*128], sh[3*2048*128], sc[3*2048*128]
#define OFF_C   69632
#define OFF_SH  331776
#define OFF_SC  1118208
#define LAYER   262144   // 2048*128

typedef __attribute__((ext_vector_type(8))) short s16x8;
typedef __attribute__((ext_vector_type(4))) float f32x4;

__device__ __forceinline__ float sigf(float x)  { return 1.0f / (1.0f + __expf(-x)); }
__device__ __forceinline__ float tanhf_(float x){ return 2.0f / (1.0f + __expf(-2.0f * x)) - 1.0f; }

__device__ __forceinline__ short f2b(float f) {
    return (short)__bfloat16_as_ushort(__float2bfloat16(f));
}

struct F8 { float4 lo, hi; };

// ---------------------------------------------------------------------------
// One LSTM cell, round-2-verified body (64 rows x 16 j per block, 256 blocks).
// gates = [A0|A1|A2] @ [Wih|Whh]^T + bih + bhh; acc[t] = gate t of one j ->
// lane-local epilogue. LDS [64][32] bf16 with 16B-slot XOR swizzle.
// ---------------------------------------------------------------------------
__device__ void lstm_cell_body(
    const float* __restrict__ A0, int w0,
    const float* __restrict__ A1, int w1,
    const float* __restrict__ A2,
    const float* __restrict__ Wih, int in_dim,
    const float* __restrict__ Whh,
    const float* __restrict__ bih, const float* __restrict__ bhh,
    const float* __restrict__ c_prev,
    float* __restrict__ h_out, float* __restrict__ c_out,
    int K, short* lsA, short* lsB)
{
    const int tid = threadIdx.x;
    const int bm = blockIdx.x * 64;   // row tile (32)
    const int j0 = blockIdx.y * 16;   // j tile (8)

    const int sRow = tid >> 2;
    const int sKc  = (tid & 3) << 3;
    const int sOff = sRow * 32 + ((((tid & 3)) ^ (sRow & 3)) << 3);

    const int w_row = (sRow >> 4) * 128 + j0 + (sRow & 15);

    const int wav = tid >> 6, lan = tid & 63;
    const int fr  = lan & 15;
    const int fkb = lan >> 4;
    const int aOff = (wav * 16 + fr) * 32 + ((fkb ^ (fr & 3)) << 3);
    const int bOffBase = fr * 32 + ((fkb ^ (fr & 3)) << 3);

    const int j = j0 + fr;

    f32x4 acc[4];
#pragma unroll
    for (int t = 0; t < 4; ++t) {
        float bv = bih[t * 128 + j] + bhh[t * 128 + j];
        acc[t] = (f32x4){bv, bv, bv, bv};
    }

    auto loadA = [&](int kt) -> F8 {
        int kg = kt * 32 + sKc;
        const float* p;
        if (kg < w0)           p = A0 + (size_t)(bm + sRow) * w0 + kg;
        else if (kg < w0 + w1) p = A1 + (size_t)(bm + sRow) * w1 + (kg - w0);
        else                   p = A2 + (size_t)(bm + sRow) * 128 + (kg - w0 - w1);
        F8 r; r.lo = *(const float4*)p; r.hi = *(const float4*)(p + 4); return r;
    };
    auto loadB = [&](int kt) -> F8 {
        int kg = kt * 32 + sKc;
        const float* p;
        if (kg < in_dim) p = Wih + (size_t)w_row * in_dim + kg;
        else             p = Whh + (size_t)w_row * 128 + (kg - in_dim);
        F8 r; r.lo = *(const float4*)p; r.hi = *(const float4*)(p + 4); return r;
    };

    const int nk = K >> 5;
    F8 aV = loadA(0);
    F8 bV = loadB(0);

    for (int kt = 0; kt < nk; ++kt) {
        s16x8 ap, bp;
        ap[0] = f2b(aV.lo.x); ap[1] = f2b(aV.lo.y); ap[2] = f2b(aV.lo.z); ap[3] = f2b(aV.lo.w);
        ap[4] = f2b(aV.hi.x); ap[5] = f2b(aV.hi.y); ap[6] = f2b(aV.hi.z); ap[7] = f2b(aV.hi.w);
        bp[0] = f2b(bV.lo.x); bp[1] = f2b(bV.lo.y); bp[2] = f2b(bV.lo.z); bp[3] = f2b(bV.lo.w);
        bp[4] = f2b(bV.hi.x); bp[5] = f2b(bV.hi.y); bp[6] = f2b(bV.hi.z); bp[7] = f2b(bV.hi.w);
        *(s16x8*)(lsA + sOff) = ap;
        *(s16x8*)(lsB + sOff) = bp;
        __syncthreads();
        if (kt + 1 < nk) { aV = loadA(kt + 1); bV = loadB(kt + 1); }

        s16x8 af = *(const s16x8*)(lsA + aOff);
#pragma unroll
        for (int t = 0; t < 4; ++t) {
            s16x8 bf = *(const s16x8*)(lsB + bOffBase + t * 512);
            acc[t] = __builtin_amdgcn_mfma_f32_16x16x32_bf16(af, bf, acc[t], 0, 0, 0);
        }
        __syncthreads();
    }

#pragma unroll
    for (int r = 0; r < 4; ++r) {
        int row = bm + wav * 16 + fkb * 4 + r;
        float gi = acc[0][r], gf = acc[1][r], gg = acc[2][r], go = acc[3][r];
        float cp = c_prev[(size_t)row * 128 + j];
        float cn = sigf(gf) * cp + sigf(gi) * tanhf_(gg);
        float hn = sigf(go) * tanhf_(cn);
        c_out[(size_t)row * 128 + j] = cn;
        h_out[(size_t)row * 128 + j] = hn;
    }
}

// Cooperative: all 3 cells in one launch, grid-synced between cells.
// Grid (32,8) = 256 blocks x 256 thr -> 1 block/CU, co-resident.
__global__ __launch_bounds__(256) void lstm_coop_kernel(
    const float* __restrict__ y_1, const float* __restrict__ c_1,
    const float* __restrict__ sh_1, const float* __restrict__ sc_1,
    const float* __restrict__ Wih0, const float* __restrict__ Whh0,
    const float* __restrict__ bih0, const float* __restrict__ bhh0,
    const float* __restrict__ Wih1, const float* __restrict__ Whh1,
    const float* __restrict__ bih1, const float* __restrict__ bhh1,
    const float* __restrict__ Wih2, const float* __restrict__ Whh2,
    const float* __restrict__ bih2, const float* __restrict__ bhh2,
    float* __restrict__ outSH, float* __restrict__ outSC)
{
    __shared__ short lsA[64 * 32];
    __shared__ short lsB[64 * 32];
    cg::grid_group grid = cg::this_grid();

    lstm_cell_body(y_1, 512, c_1, 128, sh_1, Wih0, 640, Whh0, bih0, bhh0,
                   sc_1, outSH, outSC, 768, lsA, lsB);
    __threadfence();
    grid.sync();
    lstm_cell_body(outSH, 128, nullptr, 0, sh_1 + LAYER, Wih1, 128, Whh1,
                   bih1, bhh1, sc_1 + LAYER, outSH + LAYER, outSC + LAYER,
                   256, lsA, lsB);
    __threadfence();
    grid.sync();
    lstm_cell_body(outSH + LAYER, 128, nullptr, 0, sh_1 + 2 * LAYER, Wih2, 128,
                   Whh2, bih2, bhh2, sc_1 + 2 * LAYER, outSH + 2 * LAYER,
                   outSC + 2 * LAYER, 256, lsA, lsB);
}

// ---------------------------------------------------------------------------
// Fused attention (round-2 best-measured version): scores = hk[b]·sc2[b]
// (coalesced f4 stream + width-32 shfl reduce), softmax+mask+renorm, PV.
// ---------------------------------------------------------------------------
__global__ __launch_bounds__(256) void attn_kernel(
    const float* __restrict__ hk, const float* __restrict__ hv,
    const float* __restrict__ mask, const float* __restrict__ sc2,
    float* __restrict__ c_out)
{
    const int b = blockIdx.x;
    const int tid = threadIdx.x;
    __shared__ float sP[512];
    __shared__ float sRed[8];
    __shared__ float sC[8][128];

    const float* hkb = hk + (size_t)b * (TSZ * OSZ);
    const int og = (tid & 31) * 4;
    const int tg = tid >> 5;
    float4 q = *(const float4*)(sc2 + (size_t)b * 128 + og);

    for (int it = 0; it < 64; ++it) {
        float4 v = *(const float4*)(hkb + it * 1024 + tid * 4);
        float d = v.x * q.x + v.y * q.y + v.z * q.z + v.w * q.w;
        d += __shfl_xor(d, 1, 32);
        d += __shfl_xor(d, 2, 32);
        d += __shfl_xor(d, 4, 32);
        d += __shfl_xor(d, 8, 32);
        d += __shfl_xor(d, 16, 32);
        if ((tid & 31) == 0) sP[it * 8 + tg] = d;
    }
    __syncthreads();

    // softmax over 512 with mask-then-renorm
    float m = fmaxf(sP[tid], sP[tid + 256]);
#pragma unroll
    for (int off = 1; off < 64; off <<= 1) m = fmaxf(m, __shfl_xor(m, off, 64));
    if ((tid & 63) == 0) sRed[tid >> 6] = m;
    __syncthreads();
    m = fmaxf(fmaxf(sRed[0], sRed[1]), fmaxf(sRed[2], sRed[3]));

    const float* mk = mask + (size_t)b * TSZ;
    float e0 = __expf(sP[tid] - m) * mk[tid];
    float e1 = __expf(sP[tid + 256] - m) * mk[tid + 256];
    float s = e0 + e1;
#pragma unroll
    for (int off = 1; off < 64; off <<= 1) s += __shfl_xor(s, off, 64);
    if ((tid & 63) == 0) sRed[4 + (tid >> 6)] = s;
    __syncthreads();
    float inv = 1.0f / (sRed[4] + sRed[5] + sRed[6] + sRed[7]);
    sP[tid]       = e0 * inv;
    sP[tid + 256] = e1 * inv;
    __syncthreads();

    // PV
    float4 acc = {0.f, 0.f, 0.f, 0.f};
    const float* hvb = hv + (size_t)b * (TSZ * OSZ);
    for (int it = 0; it < 64; ++it) {
        float p = sP[it * 8 + tg];
        float4 v = *(const float4*)(hvb + it * 1024 + tid * 4);
        acc.x += p * v.x; acc.y += p * v.y; acc.z += p * v.z; acc.w += p * v.w;
    }
    *(float4*)&sC[tg][og] = acc;
    __syncthreads();
    if (tid < 128) {
        float r = 0.f;
#pragma unroll
        for (int g = 0; g < 8; ++g) r += sC[g][tid];
        c_out[(size_t)b * 128 + tid] = r;
    }
}

// ---------------------------------------------------------------------------
// Cooperative head: phase A computes out_pre + BN partials; grid sync;
// phase B reduces partials (deterministic fixed order), normalizes, ReLU,
// @w3^T + b3, softmax(V=34). 256 blocks x 256 thr -> co-resident.
// ---------------------------------------------------------------------------
__global__ __launch_bounds__(256) void head_coop_kernel(
    const float* __restrict__ sh2, const float* __restrict__ cvec,
    const float* __restrict__ w1, const float* __restrict__ b1,
    const float* __restrict__ w2, const float* __restrict__ b2,
    float* __restrict__ out_pre, float* __restrict__ sum_part,
    float* __restrict__ sq_part, const float* __restrict__ gamma,
    const float* __restrict__ beta, const float* __restrict__ w3,
    const float* __restrict__ b3, float* __restrict__ out0)
{
    __shared__ float xs[8][128];
    __shared__ float xc[8][128];
    __shared__ float ps[2][128];
    __shared__ float pq[2][128];
    __shared__ float sMu[128], sRs[128];
    __shared__ float lg[8][34];

    cg::grid_group gridg = cg::this_grid();
    const int tid = threadIdx.x;
    const int rb = blockIdx.x * 8;

    // ---- phase A: out_pre = sh2@w1^T + c@w2^T + b1 + b2, partial BN sums ----
    {
        int row = tid >> 5, off = (tid & 31) * 4;
        *(float4*)&xs[row][off] = *(const float4*)(sh2 + (size_t)(rb + row) * 128 + off);
        *(float4*)&xc[row][off] = *(const float4*)(cvec + (size_t)(rb + row) * 128 + off);
    }
    __syncthreads();

    const int col = tid & 127, rg = tid >> 7;
    {
        float acc[4];
        float bb = b1[col] + b2[col];
#pragma unroll
        for (int r = 0; r < 4; ++r) acc[r] = bb;
        const float* w1r = w1 + (size_t)col * 128;
        const float* w2r = w2 + (size_t)col * 128;
        for (int k4 = 0; k4 < 32; ++k4) {
            float4 wa = *(const float4*)(w1r + k4 * 4);
            float4 wb = *(const float4*)(w2r + k4 * 4);
#pragma unroll
            for (int r = 0; r < 4; ++r) {
                float4 xa = *(const float4*)&xs[rg * 4 + r][k4 * 4];
                float4 xb = *(const float4*)&xc[rg * 4 + r][k4 * 4];
                acc[r] += xa.x * wa.x + xa.y * wa.y + xa.z * wa.z + xa.w * wa.w
                        + xb.x * wb.x + xb.y * wb.y + xb.z * wb.z + xb.w * wb.w;
            }
        }
        float s = 0.f, q = 0.f;
#pragma unroll
        for (int r = 0; r < 4; ++r) {
            out_pre[(size_t)(rb + rg * 4 + r) * 128 + col] = acc[r];
            s += acc[r]; q += acc[r] * acc[r];
        }
        ps[rg][col] = s; pq[rg][col] = q;
        __syncthreads();
        if (rg == 0) {
            sum_part[blockIdx.x * 128 + col] = ps[0][col] + ps[1][col];
            sq_part[blockIdx.x * 128 + col]  = pq[0][col] + pq[1][col];
        }
    }
    __threadfence();
    gridg.sync();

    // ---- phase B: BN stats (fixed-order reduce), normalize, V-proj, softmax ----
    {
        float s = 0.f, q = 0.f;
        for (int p = rg * 128; p < rg * 128 + 128; ++p) {
            s += sum_part[p * 128 + col];
            q += sq_part[p * 128 + col];
        }
        ps[rg][col] = s; pq[rg][col] = q;
        __syncthreads();
        if (rg == 0) {
            float st = ps[0][col] + ps[1][col];
            float qt = pq[0][col] + pq[1][col];
            float mu = st * (1.0f / 2048.0f);
            float var = qt * (1.0f / 2048.0f) - mu * mu;
            sMu[col] = mu;
            sRs[col] = rsqrtf(var + 1e-5f);
        }
        __syncthreads();
    }

    {
        int row = tid >> 5, off = (tid & 31) * 4;
        float4 v   = *(const float4*)(out_pre + (size_t)(rb + row) * 128 + off);
        float4 mu4 = *(const float4*)&sMu[off];
        float4 rs4 = *(const float4*)&sRs[off];
        float4 g4  = *(const float4*)(gamma + off);
        float4 b4  = *(const float4*)(beta + off);
        float4 o;
        o.x = fmaxf(g4.x * (v.x - mu4.x) * rs4.x + b4.x, 0.0f);
        o.y = fmaxf(g4.y * (v.y - mu4.y) * rs4.y + b4.y, 0.0f);
        o.z = fmaxf(g4.z * (v.z - mu4.z) * rs4.z + b4.z, 0.0f);
        o.w = fmaxf(g4.w * (v.w - mu4.w) * rs4.w + b4.w, 0.0f);
        *(float4*)&xs[row][off] = o;   // reuse xs as normalized buffer
    }
    __syncthreads();

    for (int idx = tid; idx < 8 * VSZ; idx += 256) {
        int row = idx / VSZ, vv = idx % VSZ;
        const float* w3r = w3 + (size_t)vv * 128;
        float acc = b3[vv];
        for (int k4 = 0; k4 < 32; ++k4) {
            float4 x4 = *(const float4*)&xs[row][k4 * 4];
            float4 wv = *(const float4*)(w3r + k4 * 4);
            acc += x4.x * wv.x + x4.y * wv.y + x4.z * wv.z + x4.w * wv.w;
        }
        lg[row][vv] = acc;
    }
    __syncthreads();

    const int row = tid >> 5, lane = tid & 31;
    float m = -1e30f;
    for (int vv = lane; vv < VSZ; vv += 32) m = fmaxf(m, lg[row][vv]);
#pragma unroll
    for (int off = 1; off < 32; off <<= 1) m = fmaxf(m, __shfl_xor(m, off, 32));
    float e0 = __expf(lg[row][lane] - m);
    float e1 = (lane + 32 < VSZ) ? __expf(lg[row][lane + 32] - m) : 0.0f;
    float s = e0 + e1;
#pragma unroll
    for (int off = 1; off < 32; off <<= 1) s += __shfl_xor(s, off, 32);
    float inv = 1.0f / s;
    out0[(size_t)(rb + row) * VSZ + lane] = e0 * inv;
    if (lane + 32 < VSZ) out0[(size_t)(rb + row) * VSZ + lane + 32] = e1 * inv;
}

// ---------------------------------------------------------------------------
extern "C" void kernel_launch(void* const* d_in, const int* in_sizes, int n_in,
                              void* d_out, int out_size, void* d_ws, size_t ws_size,
                              hipStream_t stream)
{
    const float* hk   = (const float*)d_in[0];
    const float* hv   = (const float*)d_in[1];
    const float* y_1  = (const float*)d_in[2];
    const float* c_1  = (const float*)d_in[3];
    const float* sh_1 = (const float*)d_in[4];
    const float* sc_1 = (const float*)d_in[5];
    const float* mask = (const float*)d_in[6];
    const float* Wih0 = (const float*)d_in[7];
    const float* Whh0 = (const float*)d_in[8];
    const float* bih0 = (const float*)d_in[9];
    const float* bhh0 = (const float*)d_in[10];
    const float* Wih1 = (const float*)d_in[11];
    const float* Whh1 = (const float*)d_in[12];
    const float* bih1 = (const float*)d_in[13];
    const float* bhh1 = (const float*)d_in[14];
    const float* Wih2 = (const float*)d_in[15];
    const float* Whh2 = (const float*)d_in[16];
    const float* bih2 = (const float*)d_in[17];
    const float* bhh2 = (const float*)d_in[18];
    const float* w1   = (const float*)d_in[19];
    const float* b1   = (const float*)d_in[20];
    const float* w2   = (const float*)d_in[21];
    const float* b2   = (const float*)d_in[22];
    const float* w3   = (const float*)d_in[23];
    const float* b3   = (const float*)d_in[24];
    const float* gamma= (const float*)d_in[25];
    const float* beta = (const float*)d_in[26];

    float* out   = (float*)d_out;
    float* outC  = out + OFF_C;
    float* outSH = out + OFF_SH;
    float* outSC = out + OFF_SC;

    float* ws       = (float*)d_ws;
    float* out_pre  = ws;                       // 2048*128
    float* sum_part = ws + 262144;              // 256*128
    float* sq_part  = sum_part + 32768;         // 256*128

    // LSTM: one cooperative launch, 3 grid-synced cells (round-2 bodies)
    {
        void* args[] = {
            (void*)&y_1, (void*)&c_1, (void*)&sh_1, (void*)&sc_1,
            (void*)&Wih0, (void*)&Whh0, (void*)&bih0, (void*)&bhh0,
            (void*)&Wih1, (void*)&Whh1, (void*)&bih1, (void*)&bhh1,
            (void*)&Wih2, (void*)&Whh2, (void*)&bih2, (void*)&bhh2,
            (void*)&outSH, (void*)&outSC
        };
        hipLaunchCooperativeKernel((void*)lstm_coop_kernel, dim3(32, 8),
                                   dim3(256), args, 0, stream);
    }
    // attention (query = sc2)
    attn_kernel<<<BSZ, 256, 0, stream>>>(hk, hv, mask, outSC + 2 * LAYER, outC);
    // head: one cooperative launch, 2 grid-synced phases
    {
        const float* sh2 = outSH + 2 * LAYER;
        void* args[] = {
            (void*)&sh2, (void*)&outC, (void*)&w1, (void*)&b1,
            (void*)&w2, (void*)&b2, (void*)&out_pre, (void*)&sum_part,
            (void*)&sq_part, (void*)&gamma, (void*)&beta, (void*)&w3,
            (void*)&b3, (void*)&out
        };
        hipLaunchCooperativeKernel((void*)head_coop_kernel, dim3(256),
                                   dim3(256), args, 0, stream);
    }
}

// Round 7
// 276.722 us; speedup vs baseline: 1.5519x; 1.5519x over previous
//
#include <hip/hip_runtime.h>
#include <hip/hip_bf16.h>

// Sizes (fixed by the problem)
#define BSZ 2048
#define TSZ 512
#define OSZ 128
#define ESZ 512
#define HSZ 128
#define VSZ 34

// d_out layout (f32): out[2048*34], c[2048*128], sh[3*2048*128], sc[3*2048*128]
#define OFF_C   69632
#define OFF_SH  331776
#define OFF_SC  1118208
#define LAYER   262144   // 2048*128

typedef __attribute__((ext_vector_type(8))) short s16x8;
typedef __attribute__((ext_vector_type(4))) float f32x4;

__device__ __forceinline__ float sigf(float x)  { return 1.0f / (1.0f + __expf(-x)); }
__device__ __forceinline__ float tanhf_(float x){ return 2.0f / (1.0f + __expf(-2.0f * x)) - 1.0f; }

__device__ __forceinline__ short f2b(float f) {
    return (short)__bfloat16_as_ushort(__float2bfloat16(f));
}

struct F8 { float4 lo, hi; };

// ---------------------------------------------------------------------------
// LSTM cell via bf16 MFMA (round-2 verified config: grid (32,8), 64 rows x
// 16 j per block). gates = [A0|A1|A2] @ [Wih|Whh]^T + bih + bhh; acc[t] =
// gate t of one j -> lane-local epilogue. LDS [64][32] bf16, XOR swizzle.
// ---------------------------------------------------------------------------
__global__ __launch_bounds__(256) void lstm_cell_mfma(
    const float* __restrict__ A0, int w0,
    const float* __restrict__ A1, int w1,
    const float* __restrict__ A2,              // width 128
    const float* __restrict__ Wih, int in_dim, // [512, in_dim]
    const float* __restrict__ Whh,             // [512, 128]
    const float* __restrict__ bih, const float* __restrict__ bhh,
    const float* __restrict__ c_prev,          // [2048,128]
    float* __restrict__ h_out, float* __restrict__ c_out,
    int K)
{
    __shared__ short lsA[64 * 32];
    __shared__ short lsB[64 * 32];

    const int tid = threadIdx.x;
    const int bm = blockIdx.x * 64;
    const int j0 = blockIdx.y * 16;

    const int sRow = tid >> 2;
    const int sKc  = (tid & 3) << 3;              // 0,8,16,24
    const int sOff = sRow * 32 + ((((tid & 3)) ^ (sRow & 3)) << 3);

    // B source row: nn = sRow -> (gate = nn>>4, j = j0 + (nn&15))
    const int w_row = (sRow >> 4) * 128 + j0 + (sRow & 15);

    const int wav = tid >> 6, lan = tid & 63;
    const int fr  = lan & 15;
    const int fkb = lan >> 4;
    const int aOff = (wav * 16 + fr) * 32 + ((fkb ^ (fr & 3)) << 3);
    const int bOffBase = fr * 32 + ((fkb ^ (fr & 3)) << 3);

    const int j = j0 + fr;

    f32x4 acc[4];
#pragma unroll
    for (int t = 0; t < 4; ++t) {
        float bv = bih[t * 128 + j] + bhh[t * 128 + j];
        acc[t] = (f32x4){bv, bv, bv, bv};
    }

    auto loadA = [&](int kt) -> F8 {
        int kg = kt * 32 + sKc;
        const float* p;
        if (kg < w0)           p = A0 + (size_t)(bm + sRow) * w0 + kg;
        else if (kg < w0 + w1) p = A1 + (size_t)(bm + sRow) * w1 + (kg - w0);
        else                   p = A2 + (size_t)(bm + sRow) * 128 + (kg - w0 - w1);
        F8 r; r.lo = *(const float4*)p; r.hi = *(const float4*)(p + 4); return r;
    };
    auto loadB = [&](int kt) -> F8 {
        int kg = kt * 32 + sKc;
        const float* p;
        if (kg < in_dim) p = Wih + (size_t)w_row * in_dim + kg;
        else             p = Whh + (size_t)w_row * 128 + (kg - in_dim);
        F8 r; r.lo = *(const float4*)p; r.hi = *(const float4*)(p + 4); return r;
    };

    const int nk = K >> 5;
    F8 aV = loadA(0);
    F8 bV = loadB(0);

    for (int kt = 0; kt < nk; ++kt) {
        s16x8 ap, bp;
        ap[0] = f2b(aV.lo.x); ap[1] = f2b(aV.lo.y); ap[2] = f2b(aV.lo.z); ap[3] = f2b(aV.lo.w);
        ap[4] = f2b(aV.hi.x); ap[5] = f2b(aV.hi.y); ap[6] = f2b(aV.hi.z); ap[7] = f2b(aV.hi.w);
        bp[0] = f2b(bV.lo.x); bp[1] = f2b(bV.lo.y); bp[2] = f2b(bV.lo.z); bp[3] = f2b(bV.lo.w);
        bp[4] = f2b(bV.hi.x); bp[5] = f2b(bV.hi.y); bp[6] = f2b(bV.hi.z); bp[7] = f2b(bV.hi.w);
        *(s16x8*)(lsA + sOff) = ap;
        *(s16x8*)(lsB + sOff) = bp;
        __syncthreads();
        if (kt + 1 < nk) { aV = loadA(kt + 1); bV = loadB(kt + 1); }

        s16x8 af = *(const s16x8*)(lsA + aOff);
#pragma unroll
        for (int t = 0; t < 4; ++t) {
            s16x8 bf = *(const s16x8*)(lsB + bOffBase + t * 512);
            acc[t] = __builtin_amdgcn_mfma_f32_16x16x32_bf16(af, bf, acc[t], 0, 0, 0);
        }
        __syncthreads();
    }

#pragma unroll
    for (int r = 0; r < 4; ++r) {
        int row = bm + wav * 16 + fkb * 4 + r;
        float gi = acc[0][r], gf = acc[1][r], gg = acc[2][r], go = acc[3][r];
        float cp = c_prev[(size_t)row * 128 + j];
        float cn = sigf(gf) * cp + sigf(gi) * tanhf_(gg);
        float hn = sigf(go) * tanhf_(cn);
        c_out[(size_t)row * 128 + j] = cn;
        h_out[(size_t)row * 128 + j] = hn;
    }
}

// ---------------------------------------------------------------------------
// Fused attention (round-2 best-measured version, untouched): scores =
// hk[b]·sc2[b] (coalesced f4 stream + width-32 shfl reduce), softmax with
// mask-then-renorm, PV coalesced.
// ---------------------------------------------------------------------------
__global__ __launch_bounds__(256) void attn_kernel(
    const float* __restrict__ hk, const float* __restrict__ hv,
    const float* __restrict__ mask, const float* __restrict__ sc2,
    float* __restrict__ c_out)
{
    const int b = blockIdx.x;
    const int tid = threadIdx.x;
    __shared__ float sP[512];
    __shared__ float sRed[8];
    __shared__ float sC[8][128];

    const float* hkb = hk + (size_t)b * (TSZ * OSZ);
    const int og = (tid & 31) * 4;
    const int tg = tid >> 5;
    float4 q = *(const float4*)(sc2 + (size_t)b * 128 + og);

    for (int it = 0; it < 64; ++it) {
        float4 v = *(const float4*)(hkb + it * 1024 + tid * 4);
        float d = v.x * q.x + v.y * q.y + v.z * q.z + v.w * q.w;
        d += __shfl_xor(d, 1, 32);
        d += __shfl_xor(d, 2, 32);
        d += __shfl_xor(d, 4, 32);
        d += __shfl_xor(d, 8, 32);
        d += __shfl_xor(d, 16, 32);
        if ((tid & 31) == 0) sP[it * 8 + tg] = d;
    }
    __syncthreads();

    // softmax over 512 with mask-then-renorm
    float m = fmaxf(sP[tid], sP[tid + 256]);
#pragma unroll
    for (int off = 1; off < 64; off <<= 1) m = fmaxf(m, __shfl_xor(m, off, 64));
    if ((tid & 63) == 0) sRed[tid >> 6] = m;
    __syncthreads();
    m = fmaxf(fmaxf(sRed[0], sRed[1]), fmaxf(sRed[2], sRed[3]));

    const float* mk = mask + (size_t)b * TSZ;
    float e0 = __expf(sP[tid] - m) * mk[tid];
    float e1 = __expf(sP[tid + 256] - m) * mk[tid + 256];
    float s = e0 + e1;
#pragma unroll
    for (int off = 1; off < 64; off <<= 1) s += __shfl_xor(s, off, 64);
    if ((tid & 63) == 0) sRed[4 + (tid >> 6)] = s;
    __syncthreads();
    float inv = 1.0f / (sRed[4] + sRed[5] + sRed[6] + sRed[7]);
    sP[tid]       = e0 * inv;
    sP[tid + 256] = e1 * inv;
    __syncthreads();

    // PV
    float4 acc = {0.f, 0.f, 0.f, 0.f};
    const float* hvb = hv + (size_t)b * (TSZ * OSZ);
    for (int it = 0; it < 64; ++it) {
        float p = sP[it * 8 + tg];
        float4 v = *(const float4*)(hvb + it * 1024 + tid * 4);
        acc.x += p * v.x; acc.y += p * v.y; acc.z += p * v.z; acc.w += p * v.w;
    }
    *(float4*)&sC[tg][og] = acc;
    __syncthreads();
    if (tid < 128) {
        float r = 0.f;
#pragma unroll
        for (int g = 0; g < 8; ++g) r += sC[g][tid];
        c_out[(size_t)b * 128 + tid] = r;
    }
}

// ---------------------------------------------------------------------------
// Head part A: out_pre = sh2@w1^T + c@w2^T + b1 + b2, plus per-block BN
// partial sums (deterministic two-stage reduction, no atomics).
// ---------------------------------------------------------------------------
__global__ __launch_bounds__(256) void head_pre_kernel(
    const float* __restrict__ sh2, const float* __restrict__ cvec,
    const float* __restrict__ w1, const float* __restrict__ b1,
    const float* __restrict__ w2, const float* __restrict__ b2,
    float* __restrict__ out_pre, float* __restrict__ sum_part,
    float* __restrict__ sq_part)
{
    __shared__ float xs[8][128];
    __shared__ float xc[8][128];
    __shared__ float ps[2][128];
    __shared__ float pq[2][128];
    const int tid = threadIdx.x;
    const int rb = blockIdx.x * 8;
    {
        int row = tid >> 5, off = (tid & 31) * 4;
        *(float4*)&xs[row][off] = *(const float4*)(sh2 + (size_t)(rb + row) * 128 + off);
        *(float4*)&xc[row][off] = *(const float4*)(cvec + (size_t)(rb + row) * 128 + off);
    }
    __syncthreads();

    const int col = tid & 127, rg = tid >> 7;
    float acc[4];
    float bb = b1[col] + b2[col];
#pragma unroll
    for (int r = 0; r < 4; ++r) acc[r] = bb;
    const float* w1r = w1 + (size_t)col * 128;
    const float* w2r = w2 + (size_t)col * 128;
    for (int k4 = 0; k4 < 32; ++k4) {
        float4 wa = *(const float4*)(w1r + k4 * 4);
        float4 wb = *(const float4*)(w2r + k4 * 4);
#pragma unroll
        for (int r = 0; r < 4; ++r) {
            float4 xa = *(const float4*)&xs[rg * 4 + r][k4 * 4];
            float4 xb = *(const float4*)&xc[rg * 4 + r][k4 * 4];
            acc[r] += xa.x * wa.x + xa.y * wa.y + xa.z * wa.z + xa.w * wa.w
                    + xb.x * wb.x + xb.y * wb.y + xb.z * wb.z + xb.w * wb.w;
        }
    }
    float s = 0.f, q = 0.f;
#pragma unroll
    for (int r = 0; r < 4; ++r) {
        out_pre[(size_t)(rb + rg * 4 + r) * 128 + col] = acc[r];
        s += acc[r]; q += acc[r] * acc[r];
    }
    ps[rg][col] = s; pq[rg][col] = q;
    __syncthreads();
    if (rg == 0) {
        sum_part[blockIdx.x * 128 + col] = ps[0][col] + ps[1][col];
        sq_part[blockIdx.x * 128 + col]  = pq[0][col] + pq[1][col];
    }
}

// Head part B: BN stats (recomputed per block from partials, deterministic,
// fixed order) + normalize + ReLU + @w3^T + b3 + softmax(V=34)
__global__ __launch_bounds__(256) void head_post_kernel(
    const float* __restrict__ out_pre, const float* __restrict__ sum_part,
    const float* __restrict__ sq_part, const float* __restrict__ gamma,
    const float* __restrict__ beta, const float* __restrict__ w3,
    const float* __restrict__ b3, float* __restrict__ out0)
{
    __shared__ float s2[2][128], q2[2][128];
    __shared__ float sMu[128], sRs[128];
    __shared__ float xn[8][128];
    __shared__ float lg[8][34];
    const int tid = threadIdx.x;
    const int rb = blockIdx.x * 8;

    // BN stats from the 256 per-block partials (fixed order -> deterministic)
    {
        const int col = tid & 127, h = tid >> 7;
        float s = 0.f, q = 0.f;
        for (int p = h * 128; p < h * 128 + 128; ++p) {
            s += sum_part[p * 128 + col];
            q += sq_part[p * 128 + col];
        }
        s2[h][col] = s; q2[h][col] = q;
        __syncthreads();
        if (h == 0) {
            float st = s2[0][col] + s2[1][col];
            float qt = q2[0][col] + q2[1][col];
            float mu = st * (1.0f / 2048.0f);
            float var = qt * (1.0f / 2048.0f) - mu * mu;
            sMu[col] = mu;
            sRs[col] = rsqrtf(var + 1e-5f);
        }
        __syncthreads();
    }

    {
        int row = tid >> 5, off = (tid & 31) * 4;
        float4 v   = *(const float4*)(out_pre + (size_t)(rb + row) * 128 + off);
        float4 mu4 = *(const float4*)&sMu[off];
        float4 rs4 = *(const float4*)&sRs[off];
        float4 g4  = *(const float4*)(gamma + off);
        float4 b4  = *(const float4*)(beta + off);
        float4 o;
        o.x = fmaxf(g4.x * (v.x - mu4.x) * rs4.x + b4.x, 0.0f);
        o.y = fmaxf(g4.y * (v.y - mu4.y) * rs4.y + b4.y, 0.0f);
        o.z = fmaxf(g4.z * (v.z - mu4.z) * rs4.z + b4.z, 0.0f);
        o.w = fmaxf(g4.w * (v.w - mu4.w) * rs4.w + b4.w, 0.0f);
        *(float4*)&xn[row][off] = o;
    }
    __syncthreads();

    for (int idx = tid; idx < 8 * VSZ; idx += 256) {
        int row = idx / VSZ, vv = idx % VSZ;
        const float* w3r = w3 + (size_t)vv * 128;
        float acc = b3[vv];
        for (int k4 = 0; k4 < 32; ++k4) {
            float4 x4 = *(const float4*)&xn[row][k4 * 4];
            float4 wv = *(const float4*)(w3r + k4 * 4);
            acc += x4.x * wv.x + x4.y * wv.y + x4.z * wv.z + x4.w * wv.w;
        }
        lg[row][vv] = acc;
    }
    __syncthreads();

    const int row = tid >> 5, lane = tid & 31;
    float m = -1e30f;
    for (int vv = lane; vv < VSZ; vv += 32) m = fmaxf(m, lg[row][vv]);
#pragma unroll
    for (int off = 1; off < 32; off <<= 1) m = fmaxf(m, __shfl_xor(m, off, 32));
    float e0 = __expf(lg[row][lane] - m);
    float e1 = (lane + 32 < VSZ) ? __expf(lg[row][lane + 32] - m) : 0.0f;
    float s = e0 + e1;
#pragma unroll
    for (int off = 1; off < 32; off <<= 1) s += __shfl_xor(s, off, 32);
    float inv = 1.0f / s;
    out0[(size_t)(rb + row) * VSZ + lane] = e0 * inv;
    if (lane + 32 < VSZ) out0[(size_t)(rb + row) * VSZ + lane + 32] = e1 * inv;
}

// ---------------------------------------------------------------------------
extern "C" void kernel_launch(void* const* d_in, const int* in_sizes, int n_in,
                              void* d_out, int out_size, void* d_ws, size_t ws_size,
                              hipStream_t stream)
{
    const float* hk   = (const float*)d_in[0];
    const float* hv   = (const float*)d_in[1];
    const float* y_1  = (const float*)d_in[2];
    const float* c_1  = (const float*)d_in[3];
    const float* sh_1 = (const float*)d_in[4];
    const float* sc_1 = (const float*)d_in[5];
    const float* mask = (const float*)d_in[6];
    const float* Wih0 = (const float*)d_in[7];
    const float* Whh0 = (const float*)d_in[8];
    const float* bih0 = (const float*)d_in[9];
    const float* bhh0 = (const float*)d_in[10];
    const float* Wih1 = (const float*)d_in[11];
    const float* Whh1 = (const float*)d_in[12];
    const float* bih1 = (const float*)d_in[13];
    const float* bhh1 = (const float*)d_in[14];
    const float* Wih2 = (const float*)d_in[15];
    const float* Whh2 = (const float*)d_in[16];
    const float* bih2 = (const float*)d_in[17];
    const float* bhh2 = (const float*)d_in[18];
    const float* w1   = (const float*)d_in[19];
    const float* b1   = (const float*)d_in[20];
    const float* w2   = (const float*)d_in[21];
    const float* b2   = (const float*)d_in[22];
    const float* w3   = (const float*)d_in[23];
    const float* b3   = (const float*)d_in[24];
    const float* gamma= (const float*)d_in[25];
    const float* beta = (const float*)d_in[26];

    float* out   = (float*)d_out;
    float* outC  = out + OFF_C;
    float* outSH = out + OFF_SH;
    float* outSC = out + OFF_SC;

    float* ws       = (float*)d_ws;
    float* out_pre  = ws;                       // 2048*128
    float* sum_part = ws + 262144;              // 256*128
    float* sq_part  = sum_part + 32768;         // 256*128

    dim3 gG(32, 8), bG(256);
    // cell 0: A = [y_1(512) | c_1(128) | sh_1[0](128)], K=768, in_dim=640
    lstm_cell_mfma<<<gG, bG, 0, stream>>>(
        y_1, 512, c_1, 128, sh_1, Wih0, 640, Whh0, bih0, bhh0,
        sc_1, outSH, outSC, 768);
    // cell 1: A = [h0(128) | sh_1[1](128)], K=256, in_dim=128
    lstm_cell_mfma<<<gG, bG, 0, stream>>>(
        outSH, 128, nullptr, 0, sh_1 + LAYER, Wih1, 128, Whh1, bih1, bhh1,
        sc_1 + LAYER, outSH + LAYER, outSC + LAYER, 256);
    // cell 2
    lstm_cell_mfma<<<gG, bG, 0, stream>>>(
        outSH + LAYER, 128, nullptr, 0, sh_1 + 2 * LAYER, Wih2, 128, Whh2, bih2, bhh2,
        sc_1 + 2 * LAYER, outSH + 2 * LAYER, outSC + 2 * LAYER, 256);
    // attention (query = sc2)
    attn_kernel<<<BSZ, 256, 0, stream>>>(hk, hv, mask, outSC + 2 * LAYER, outC);
    // head (2 kernels: pre + stats/post fused)
    head_pre_kernel<<<256, 256, 0, stream>>>(outSH + 2 * LAYER, outC, w1, b1, w2, b2,
                                             out_pre, sum_part, sq_part);
    head_post_kernel<<<256, 256, 0, stream>>>(out_pre, sum_part, sq_part, gamma, beta,
                                              w3, b3, out);
}

// Round 8
// 276.352 us; speedup vs baseline: 1.5539x; 1.0013x over previous
//
#include <hip/hip_runtime.h>
#include <hip/hip_bf16.h>

// Sizes (fixed by the problem)
#define BSZ 2048
#define TSZ 512
#define OSZ 128
#define ESZ 512
#define HSZ 128
#define VSZ 34

// d_out layout (f32): out[2048*34], c[2048*128], sh[3*2048*128], sc[3*2048*128]
#define OFF_C   69632
#define OFF_SH  331776
#define OFF_SC  1118208
#define LAYER   262144   // 2048*128

typedef __attribute__((ext_vector_type(8))) short s16x8;
typedef __attribute__((ext_vector_type(4))) float f32x4;

__device__ __forceinline__ float sigf(float x)  { return 1.0f / (1.0f + __expf(-x)); }
__device__ __forceinline__ float tanhf_(float x){ return 2.0f / (1.0f + __expf(-2.0f * x)) - 1.0f; }

__device__ __forceinline__ short f2b(float f) {
    return (short)__bfloat16_as_ushort(__float2bfloat16(f));
}

struct F8 { float4 lo, hi; };

// ---------------------------------------------------------------------------
// LSTM cell via bf16 MFMA, occupancy-doubled config: 128 threads (2 waves),
// 32 rows x 16 j per block, grid (64,8) = 512 blocks -> 2 independent
// blocks/CU (two barrier groups overlap each other's memory stalls; the
// 256-block config had 1 block/CU and no independent waves to hide the
// cold-HBM prefetch latency). Same per-(row,j) MFMA math and f2b staging
// order as the verified round-2 kernel -> bit-identical outputs.
// ---------------------------------------------------------------------------
__global__ __launch_bounds__(128) void lstm_cell_mfma(
    const float* __restrict__ A0, int w0,
    const float* __restrict__ A1, int w1,
    const float* __restrict__ A2,              // width 128
    const float* __restrict__ Wih, int in_dim, // [512, in_dim]
    const float* __restrict__ Whh,             // [512, 128]
    const float* __restrict__ bih, const float* __restrict__ bhh,
    const float* __restrict__ c_prev,          // [2048,128]
    float* __restrict__ h_out, float* __restrict__ c_out,
    int K)
{
    __shared__ short lsA[32 * 32];
    __shared__ short lsB[64 * 32];

    const int tid = threadIdx.x;
    const int bm = blockIdx.x * 32;   // row tile (64)
    const int j0 = blockIdx.y * 16;   // j tile (8)

    // A staging: thread -> (row 0..31, k-chunk of 8)
    const int sRowA = tid >> 2;
    const int sKc   = (tid & 3) << 3;
    const int aStOff = sRowA * 32 + (((tid & 3) ^ (sRowA & 3)) << 3);

    // B staging: 2 rows per thread: nn = (tid>>2) + 32*i
    // lds row nn <-> W row: gate = nn>>4, j = j0 + (nn&15)
    int wRowB[2], bStOff[2];
#pragma unroll
    for (int i = 0; i < 2; ++i) {
        int nn = (tid >> 2) + 32 * i;
        wRowB[i] = (nn >> 4) * 128 + j0 + (nn & 15);
        bStOff[i] = nn * 32 + (((tid & 3) ^ (nn & 3)) << 3);
    }

    // fragment indices (2 waves; wave w owns rows [w*16, w*16+16))
    const int wav = tid >> 6, lan = tid & 63;
    const int fr  = lan & 15;
    const int fkb = lan >> 4;
    const int aOff = (wav * 16 + fr) * 32 + ((fkb ^ (fr & 3)) << 3);
    const int bOffBase = fr * 32 + ((fkb ^ (fr & 3)) << 3);

    const int j = j0 + fr;

    f32x4 acc[4];
#pragma unroll
    for (int t = 0; t < 4; ++t) {
        float bv = bih[t * 128 + j] + bhh[t * 128 + j];
        acc[t] = (f32x4){bv, bv, bv, bv};
    }

    auto loadA = [&](int kt) -> F8 {
        int kg = kt * 32 + sKc;
        const float* p;
        if (kg < w0)           p = A0 + (size_t)(bm + sRowA) * w0 + kg;
        else if (kg < w0 + w1) p = A1 + (size_t)(bm + sRowA) * w1 + (kg - w0);
        else                   p = A2 + (size_t)(bm + sRowA) * 128 + (kg - w0 - w1);
        F8 r; r.lo = *(const float4*)p; r.hi = *(const float4*)(p + 4); return r;
    };
    auto loadB = [&](int kt, int i) -> F8 {
        int kg = kt * 32 + sKc;
        const float* p;
        if (kg < in_dim) p = Wih + (size_t)wRowB[i] * in_dim + kg;
        else             p = Whh + (size_t)wRowB[i] * 128 + (kg - in_dim);
        F8 r; r.lo = *(const float4*)p; r.hi = *(const float4*)(p + 4); return r;
    };

    const int nk = K >> 5;
    F8 aV = loadA(0);
    F8 bV0 = loadB(0, 0);
    F8 bV1 = loadB(0, 1);

    for (int kt = 0; kt < nk; ++kt) {
        {
            s16x8 ap;
            ap[0] = f2b(aV.lo.x); ap[1] = f2b(aV.lo.y); ap[2] = f2b(aV.lo.z); ap[3] = f2b(aV.lo.w);
            ap[4] = f2b(aV.hi.x); ap[5] = f2b(aV.hi.y); ap[6] = f2b(aV.hi.z); ap[7] = f2b(aV.hi.w);
            *(s16x8*)(lsA + aStOff) = ap;
            s16x8 bp;
            bp[0] = f2b(bV0.lo.x); bp[1] = f2b(bV0.lo.y); bp[2] = f2b(bV0.lo.z); bp[3] = f2b(bV0.lo.w);
            bp[4] = f2b(bV0.hi.x); bp[5] = f2b(bV0.hi.y); bp[6] = f2b(bV0.hi.z); bp[7] = f2b(bV0.hi.w);
            *(s16x8*)(lsB + bStOff[0]) = bp;
            bp[0] = f2b(bV1.lo.x); bp[1] = f2b(bV1.lo.y); bp[2] = f2b(bV1.lo.z); bp[3] = f2b(bV1.lo.w);
            bp[4] = f2b(bV1.hi.x); bp[5] = f2b(bV1.hi.y); bp[6] = f2b(bV1.hi.z); bp[7] = f2b(bV1.hi.w);
            *(s16x8*)(lsB + bStOff[1]) = bp;
        }
        __syncthreads();
        if (kt + 1 < nk) {
            aV = loadA(kt + 1);
            bV0 = loadB(kt + 1, 0);
            bV1 = loadB(kt + 1, 1);
        }

        s16x8 af = *(const s16x8*)(lsA + aOff);
#pragma unroll
        for (int t = 0; t < 4; ++t) {
            s16x8 bf = *(const s16x8*)(lsB + bOffBase + t * 512);
            acc[t] = __builtin_amdgcn_mfma_f32_16x16x32_bf16(af, bf, acc[t], 0, 0, 0);
        }
        __syncthreads();
    }

#pragma unroll
    for (int r = 0; r < 4; ++r) {
        int row = bm + wav * 16 + fkb * 4 + r;
        float gi = acc[0][r], gf = acc[1][r], gg = acc[2][r], go = acc[3][r];
        float cp = c_prev[(size_t)row * 128 + j];
        float cn = sigf(gf) * cp + sigf(gi) * tanhf_(gg);
        float hn = sigf(go) * tanhf_(cn);
        c_out[(size_t)row * 128 + j] = cn;
        h_out[(size_t)row * 128 + j] = hn;
    }
}

// ---------------------------------------------------------------------------
// Fused attention (round-2 best-measured version, untouched): scores =
// hk[b]·sc2[b] (coalesced f4 stream + width-32 shfl reduce), softmax with
// mask-then-renorm, PV coalesced. ~88% of achievable read BW.
// ---------------------------------------------------------------------------
__global__ __launch_bounds__(256) void attn_kernel(
    const float* __restrict__ hk, const float* __restrict__ hv,
    const float* __restrict__ mask, const float* __restrict__ sc2,
    float* __restrict__ c_out)
{
    const int b = blockIdx.x;
    const int tid = threadIdx.x;
    __shared__ float sP[512];
    __shared__ float sRed[8];
    __shared__ float sC[8][128];

    const float* hkb = hk + (size_t)b * (TSZ * OSZ);
    const int og = (tid & 31) * 4;
    const int tg = tid >> 5;
    float4 q = *(const float4*)(sc2 + (size_t)b * 128 + og);

    for (int it = 0; it < 64; ++it) {
        float4 v = *(const float4*)(hkb + it * 1024 + tid * 4);
        float d = v.x * q.x + v.y * q.y + v.z * q.z + v.w * q.w;
        d += __shfl_xor(d, 1, 32);
        d += __shfl_xor(d, 2, 32);
        d += __shfl_xor(d, 4, 32);
        d += __shfl_xor(d, 8, 32);
        d += __shfl_xor(d, 16, 32);
        if ((tid & 31) == 0) sP[it * 8 + tg] = d;
    }
    __syncthreads();

    // softmax over 512 with mask-then-renorm
    float m = fmaxf(sP[tid], sP[tid + 256]);
#pragma unroll
    for (int off = 1; off < 64; off <<= 1) m = fmaxf(m, __shfl_xor(m, off, 64));
    if ((tid & 63) == 0) sRed[tid >> 6] = m;
    __syncthreads();
    m = fmaxf(fmaxf(sRed[0], sRed[1]), fmaxf(sRed[2], sRed[3]));

    const float* mk = mask + (size_t)b * TSZ;
    float e0 = __expf(sP[tid] - m) * mk[tid];
    float e1 = __expf(sP[tid + 256] - m) * mk[tid + 256];
    float s = e0 + e1;
#pragma unroll
    for (int off = 1; off < 64; off <<= 1) s += __shfl_xor(s, off, 64);
    if ((tid & 63) == 0) sRed[4 + (tid >> 6)] = s;
    __syncthreads();
    float inv = 1.0f / (sRed[4] + sRed[5] + sRed[6] + sRed[7]);
    sP[tid]       = e0 * inv;
    sP[tid + 256] = e1 * inv;
    __syncthreads();

    // PV
    float4 acc = {0.f, 0.f, 0.f, 0.f};
    const float* hvb = hv + (size_t)b * (TSZ * OSZ);
    for (int it = 0; it < 64; ++it) {
        float p = sP[it * 8 + tg];
        float4 v = *(const float4*)(hvb + it * 1024 + tid * 4);
        acc.x += p * v.x; acc.y += p * v.y; acc.z += p * v.z; acc.w += p * v.w;
    }
    *(float4*)&sC[tg][og] = acc;
    __syncthreads();
    if (tid < 128) {
        float r = 0.f;
#pragma unroll
        for (int g = 0; g < 8; ++g) r += sC[g][tid];
        c_out[(size_t)b * 128 + tid] = r;
    }
}

// ---------------------------------------------------------------------------
// Head part A: out_pre = sh2@w1^T + c@w2^T + b1 + b2, plus per-block BN
// partial sums (deterministic two-stage reduction, no atomics).
// ---------------------------------------------------------------------------
__global__ __launch_bounds__(256) void head_pre_kernel(
    const float* __restrict__ sh2, const float* __restrict__ cvec,
    const float* __restrict__ w1, const float* __restrict__ b1,
    const float* __restrict__ w2, const float* __restrict__ b2,
    float* __restrict__ out_pre, float* __restrict__ sum_part,
    float* __restrict__ sq_part)
{
    __shared__ float xs[8][128];
    __shared__ float xc[8][128];
    __shared__ float ps[2][128];
    __shared__ float pq[2][128];
    const int tid = threadIdx.x;
    const int rb = blockIdx.x * 8;
    {
        int row = tid >> 5, off = (tid & 31) * 4;
        *(float4*)&xs[row][off] = *(const float4*)(sh2 + (size_t)(rb + row) * 128 + off);
        *(float4*)&xc[row][off] = *(const float4*)(cvec + (size_t)(rb + row) * 128 + off);
    }
    __syncthreads();

    const int col = tid & 127, rg = tid >> 7;
    float acc[4];
    float bb = b1[col] + b2[col];
#pragma unroll
    for (int r = 0; r < 4; ++r) acc[r] = bb;
    const float* w1r = w1 + (size_t)col * 128;
    const float* w2r = w2 + (size_t)col * 128;
    for (int k4 = 0; k4 < 32; ++k4) {
        float4 wa = *(const float4*)(w1r + k4 * 4);
        float4 wb = *(const float4*)(w2r + k4 * 4);
#pragma unroll
        for (int r = 0; r < 4; ++r) {
            float4 xa = *(const float4*)&xs[rg * 4 + r][k4 * 4];
            float4 xb = *(const float4*)&xc[rg * 4 + r][k4 * 4];
            acc[r] += xa.x * wa.x + xa.y * wa.y + xa.z * wa.z + xa.w * wa.w
                    + xb.x * wb.x + xb.y * wb.y + xb.z * wb.z + xb.w * wb.w;
        }
    }
    float s = 0.f, q = 0.f;
#pragma unroll
    for (int r = 0; r < 4; ++r) {
        out_pre[(size_t)(rb + rg * 4 + r) * 128 + col] = acc[r];
        s += acc[r]; q += acc[r] * acc[r];
    }
    ps[rg][col] = s; pq[rg][col] = q;
    __syncthreads();
    if (rg == 0) {
        sum_part[blockIdx.x * 128 + col] = ps[0][col] + ps[1][col];
        sq_part[blockIdx.x * 128 + col]  = pq[0][col] + pq[1][col];
    }
}

// Head part B: BN stats (recomputed per block from partials, deterministic,
// fixed order) + normalize + ReLU + @w3^T + b3 + softmax(V=34)
__global__ __launch_bounds__(256) void head_post_kernel(
    const float* __restrict__ out_pre, const float* __restrict__ sum_part,
    const float* __restrict__ sq_part, const float* __restrict__ gamma,
    const float* __restrict__ beta, const float* __restrict__ w3,
    const float* __restrict__ b3, float* __restrict__ out0)
{
    __shared__ float s2[2][128], q2[2][128];
    __shared__ float sMu[128], sRs[128];
    __shared__ float xn[8][128];
    __shared__ float lg[8][34];
    const int tid = threadIdx.x;
    const int rb = blockIdx.x * 8;

    // BN stats from the 256 per-block partials (fixed order -> deterministic)
    {
        const int col = tid & 127, h = tid >> 7;
        float s = 0.f, q = 0.f;
        for (int p = h * 128; p < h * 128 + 128; ++p) {
            s += sum_part[p * 128 + col];
            q += sq_part[p * 128 + col];
        }
        s2[h][col] = s; q2[h][col] = q;
        __syncthreads();
        if (h == 0) {
            float st = s2[0][col] + s2[1][col];
            float qt = q2[0][col] + q2[1][col];
            float mu = st * (1.0f / 2048.0f);
            float var = qt * (1.0f / 2048.0f) - mu * mu;
            sMu[col] = mu;
            sRs[col] = rsqrtf(var + 1e-5f);
        }
        __syncthreads();
    }

    {
        int row = tid >> 5, off = (tid & 31) * 4;
        float4 v   = *(const float4*)(out_pre + (size_t)(rb + row) * 128 + off);
        float4 mu4 = *(const float4*)&sMu[off];
        float4 rs4 = *(const float4*)&sRs[off];
        float4 g4  = *(const float4*)(gamma + off);
        float4 b4  = *(const float4*)(beta + off);
        float4 o;
        o.x = fmaxf(g4.x * (v.x - mu4.x) * rs4.x + b4.x, 0.0f);
        o.y = fmaxf(g4.y * (v.y - mu4.y) * rs4.y + b4.y, 0.0f);
        o.z = fmaxf(g4.z * (v.z - mu4.z) * rs4.z + b4.z, 0.0f);
        o.w = fmaxf(g4.w * (v.w - mu4.w) * rs4.w + b4.w, 0.0f);
        *(float4*)&xn[row][off] = o;
    }
    __syncthreads();

    for (int idx = tid; idx < 8 * VSZ; idx += 256) {
        int row = idx / VSZ, vv = idx % VSZ;
        const float* w3r = w3 + (size_t)vv * 128;
        float acc = b3[vv];
        for (int k4 = 0; k4 < 32; ++k4) {
            float4 x4 = *(const float4*)&xn[row][k4 * 4];
            float4 wv = *(const float4*)(w3r + k4 * 4);
            acc += x4.x * wv.x + x4.y * wv.y + x4.z * wv.z + x4.w * wv.w;
        }
        lg[row][vv] = acc;
    }
    __syncthreads();

    const int row = tid >> 5, lane = tid & 31;
    float m = -1e30f;
    for (int vv = lane; vv < VSZ; vv += 32) m = fmaxf(m, lg[row][vv]);
#pragma unroll
    for (int off = 1; off < 32; off <<= 1) m = fmaxf(m, __shfl_xor(m, off, 32));
    float e0 = __expf(lg[row][lane] - m);
    float e1 = (lane + 32 < VSZ) ? __expf(lg[row][lane + 32] - m) : 0.0f;
    float s = e0 + e1;
#pragma unroll
    for (int off = 1; off < 32; off <<= 1) s += __shfl_xor(s, off, 32);
    float inv = 1.0f / s;
    out0[(size_t)(rb + row) * VSZ + lane] = e0 * inv;
    if (lane + 32 < VSZ) out0[(size_t)(rb + row) * VSZ + lane + 32] = e1 * inv;
}

// ---------------------------------------------------------------------------
extern "C" void kernel_launch(void* const* d_in, const int* in_sizes, int n_in,
                              void* d_out, int out_size, void* d_ws, size_t ws_size,
                              hipStream_t stream)
{
    const float* hk   = (const float*)d_in[0];
    const float* hv   = (const float*)d_in[1];
    const float* y_1  = (const float*)d_in[2];
    const float* c_1  = (const float*)d_in[3];
    const float* sh_1 = (const float*)d_in[4];
    const float* sc_1 = (const float*)d_in[5];
    const float* mask = (const float*)d_in[6];
    const float* Wih0 = (const float*)d_in[7];
    const float* Whh0 = (const float*)d_in[8];
    const float* bih0 = (const float*)d_in[9];
    const float* bhh0 = (const float*)d_in[10];
    const float* Wih1 = (const float*)d_in[11];
    const float* Whh1 = (const float*)d_in[12];
    const float* bih1 = (const float*)d_in[13];
    const float* bhh1 = (const float*)d_in[14];
    const float* Wih2 = (const float*)d_in[15];
    const float* Whh2 = (const float*)d_in[16];
    const float* bih2 = (const float*)d_in[17];
    const float* bhh2 = (const float*)d_in[18];
    const float* w1   = (const float*)d_in[19];
    const float* b1   = (const float*)d_in[20];
    const float* w2   = (const float*)d_in[21];
    const float* b2   = (const float*)d_in[22];
    const float* w3   = (const float*)d_in[23];
    const float* b3   = (const float*)d_in[24];
    const float* gamma= (const float*)d_in[25];
    const float* beta = (const float*)d_in[26];

    float* out   = (float*)d_out;
    float* outC  = out + OFF_C;
    float* outSH = out + OFF_SH;
    float* outSC = out + OFF_SC;

    float* ws       = (float*)d_ws;
    float* out_pre  = ws;                       // 2048*128
    float* sum_part = ws + 262144;              // 256*128
    float* sq_part  = sum_part + 32768;         // 256*128

    dim3 gG(64, 8), bG(128);   // 512 blocks x 2 waves -> 2 blocks/CU
    // cell 0: A = [y_1(512) | c_1(128) | sh_1[0](128)], K=768, in_dim=640
    lstm_cell_mfma<<<gG, bG, 0, stream>>>(
        y_1, 512, c_1, 128, sh_1, Wih0, 640, Whh0, bih0, bhh0,
        sc_1, outSH, outSC, 768);
    // cell 1: A = [h0(128) | sh_1[1](128)], K=256, in_dim=128
    lstm_cell_mfma<<<gG, bG, 0, stream>>>(
        outSH, 128, nullptr, 0, sh_1 + LAYER, Wih1, 128, Whh1, bih1, bhh1,
        sc_1 + LAYER, outSH + LAYER, outSC + LAYER, 256);
    // cell 2
    lstm_cell_mfma<<<gG, bG, 0, stream>>>(
        outSH + LAYER, 128, nullptr, 0, sh_1 + 2 * LAYER, Wih2, 128, Whh2, bih2, bhh2,
        sc_1 + 2 * LAYER, outSH + 2 * LAYER, outSC + 2 * LAYER, 256);
    // attention (query = sc2)
    attn_kernel<<<BSZ, 256, 0, stream>>>(hk, hv, mask, outSC + 2 * LAYER, outC);
    // head (2 kernels: pre + stats/post fused)
    head_pre_kernel<<<256, 256, 0, stream>>>(outSH + 2 * LAYER, outC, w1, b1, w2, b2,
                                             out_pre, sum_part, sq_part);
    head_post_kernel<<<256, 256, 0, stream>>>(out_pre, sum_part, sq_part, gamma, beta,
                                              w3, b3, out);
}